// Round 11
// baseline (38.676 us; speedup 1.0000x reference)
//
#include <hip/hip_runtime.h>
#include <hip/hip_bf16.h>

#define BDIM 256

typedef __attribute__((ext_vector_type(8))) _Float16 f16x8;
typedef __attribute__((ext_vector_type(4))) _Float16 f16x4;
typedef __attribute__((ext_vector_type(4))) float f32x4;

// Local windowed attention with RoPE. b=32, n=4096, d=64, WINDOW=128, 1 backward window.
// R11: ONE WINDOW per block, 256 threads (4 waves x 2 m-tiles), SINGLE 36.3KB LDS slot
// with sequential halves -> 4 blocks/CU, grid 1024: four independent barrier domains
// per CU that de-phase (one stages while others compute). R9/R10 had 2 lockstep
// blocks/CU and every stage phase fully exposed.
// Carried invariants: swapped QK^T D=mfma(K,Q) (per-query stats in c-layout, accO in
// row-layout; every per-query factor shuffled c->row before touching accO), permuted
// Vt columns so the PV B-operand is one ds_read_b128, online softmax, no register
// payload held across barriers (spill sentinel: WRITE_SIZE == 32.8MB output only).
__global__ __launch_bounds__(256, 4)
void la_kernel(const float* __restrict__ qg, const float* __restrict__ kg,
               const float* __restrict__ vg, float* __restrict__ outg)
{
    __shared__ _Float16 Ks[128][72];   // 18432 B
    __shared__ _Float16 Vt[64][140];   // 17920 B  -> 36352 B total

    const int ww = blockIdx.x, bb = blockIdx.y;
    const int tid = threadIdx.x;
    const int wv = tid >> 6, lane = tid & 63, g = lane >> 4, c = lane & 15;
    const size_t rowb = (size_t)bb * 4096;
    const int srow0 = ww * 128 - 128;            // first source row of half 0
    const float NEG = -3.0e38f;
    const float NLT32 = -0.28782313662425572f;   // -ln(10000)/32

    const int cbK = (tid & 7) << 2;
    float invfK[4];
    #pragma unroll
    for (int u = 0; u < 4; ++u) invfK[u] = __expf((float)(cbK + u) * NLT32);

    // ---- Q: two 16-row m-tiles per wave (rows 32wv+16mt+c), RoPE t = 128+qrow ----
    f16x8 qa0[2], qa1[2];
    {
        float invfQ[8];
        #pragma unroll
        for (int u = 0; u < 8; ++u) invfQ[u] = __expf((float)(8 * g + u) * NLT32);
        #pragma unroll
        for (int mt = 0; mt < 2; ++mt) {
            const int qrow = wv * 32 + mt * 16 + c;
            const float* p = qg + (rowb + ww * 128 + qrow) * 64 + 8 * g;
            float4 a0 = *(const float4*)p;
            float4 a1 = *(const float4*)(p + 4);
            float4 b0 = *(const float4*)(p + 32);
            float4 b1 = *(const float4*)(p + 36);
            float ra[8] = {a0.x,a0.y,a0.z,a0.w,a1.x,a1.y,a1.z,a1.w};
            float rb[8] = {b0.x,b0.y,b0.z,b0.w,b1.x,b1.y,b1.z,b1.w};
            float tq = (float)(128 + qrow);
            #pragma unroll
            for (int u = 0; u < 8; ++u) {
                float sn, cs; __sincosf(tq * invfQ[u], &sn, &cs);
                float a = ra[u] * 0.125f, b = rb[u] * 0.125f;
                qa0[mt][u] = (_Float16)(a * cs - b * sn);
                qa1[mt][u] = (_Float16)(b * cs + a * sn);
            }
        }
    }

    // ---- flash state per m-tile (m, s in c-layout; accO in row-layout) ----
    f32x4 accO[2][4];
    #pragma unroll
    for (int mt = 0; mt < 2; ++mt)
        #pragma unroll
        for (int nt = 0; nt < 4; ++nt) accO[mt][nt] = (f32x4){0.f,0.f,0.f,0.f};
    float m[2] = {NEG, NEG}, s[2] = {0.f, 0.f};

    #pragma unroll 1
    for (int h = 0; h < 2; ++h) {
        if (h == 0 && ww == 0) continue;         // half 0 of window 0 is all padding
        if (h == 1 && ww != 0) __syncthreads();  // half-0 reads done before overwrite

        // ---- stage K half (RoPE, t = 128h + j), b64 LDS writes ----
        #pragma unroll
        for (int it = 0; it < 4; ++it) {
            int j = (tid + it * 256) >> 3;       // 0..127
            int t = 128 * h + j;
            const float* p = kg + (rowb + srow0 + t) * 64 + cbK;
            float4 x1 = *(const float4*)p;
            float4 x2 = *(const float4*)(p + 32);
            const float* x1p = &x1.x;
            const float* x2p = &x2.x;
            f16x4 lo, hi;
            #pragma unroll
            for (int u = 0; u < 4; ++u) {
                float sn, cs; __sincosf((float)t * invfK[u], &sn, &cs);
                lo[u] = (_Float16)(x1p[u] * cs - x2p[u] * sn);
                hi[u] = (_Float16)(x2p[u] * cs + x1p[u] * sn);
            }
            *(f16x4*)&Ks[j][cbK]      = lo;
            *(f16x4*)&Ks[j][cbK + 32] = hi;
        }

        // ---- stage V half: 4x4 transpose blocks into permuted columns ----
        #pragma unroll
        for (int it = 0; it < 2; ++it) {
            int task = tid + it * 256;
            int jq = task >> 4, eq = task & 15;  // jq: 4-row group [0,32)
            int colb = ((jq & 24) << 2) + 8 * (jq & 3) + 4 * ((jq >> 2) & 1);
            float4 x[4];
            #pragma unroll
            for (int w = 0; w < 4; ++w)
                x[w] = *(const float4*)(vg + (rowb + srow0 + 128 * h + 4 * jq + w) * 64 + 4 * eq);
            #pragma unroll
            for (int u = 0; u < 4; ++u) {
                f16x4 o;
                o[0] = (_Float16)((const float*)&x[0])[u];
                o[1] = (_Float16)((const float*)&x[1])[u];
                o[2] = (_Float16)((const float*)&x[2])[u];
                o[3] = (_Float16)((const float*)&x[3])[u];
                *(f16x4*)&Vt[4 * eq + u][colb] = o;
            }
        }

        __syncthreads();

        // ---- per m-tile, two 64-col chunks: QK^T -> online softmax -> PV ----
        #pragma unroll
        for (int mt = 0; mt < 2; ++mt) {
            const int qrow = wv * 32 + mt * 16 + c;
            #pragma unroll
            for (int ch = 0; ch < 2; ++ch) {
                // wave-uniform: causal chunk1 fully masked for m-tiles ending < 64
                if (h == 1 && ch == 1 && (wv * 32 + mt * 16) <= 48) continue;

                f32x4 acc[4];
                #pragma unroll
                for (int jt = 0; jt < 4; ++jt) acc[jt] = (f32x4){0.f,0.f,0.f,0.f};

                #pragma unroll
                for (int jt = 0; jt < 4; ++jt) {
                    int row = ch * 64 + jt * 16 + c;
                    f16x8 kb0 = *(const f16x8*)&Ks[row][8 * g];
                    f16x8 kb1 = *(const f16x8*)&Ks[row][32 + 8 * g];
                    acc[jt] = __builtin_amdgcn_mfma_f32_16x16x32_f16(kb0, qa0[mt], acc[jt], 0, 0, 0);
                    acc[jt] = __builtin_amdgcn_mfma_f32_16x16x32_f16(kb1, qa1[mt], acc[jt], 0, 0, 0);
                }

                if (h == 1) {                    // causal: local jj masked when > qrow
                    #pragma unroll
                    for (int jt = 0; jt < 4; ++jt)
                        #pragma unroll
                        for (int r = 0; r < 4; ++r) {
                            int jj = ch * 64 + jt * 16 + 4 * g + r;
                            if (jj > qrow) acc[jt][r] = NEG;
                        }
                }

                float mx = NEG;
                #pragma unroll
                for (int jt = 0; jt < 4; ++jt)
                    #pragma unroll
                    for (int r = 0; r < 4; ++r) mx = fmaxf(mx, acc[jt][r]);
                mx = fmaxf(mx, __shfl_xor(mx, 16));
                mx = fmaxf(mx, __shfl_xor(mx, 32));

                float mnew = fmaxf(m[mt], mx);
                float alpha = __expf(m[mt] - mnew);

                float ps = 0.f;
                f16x8 pa[2];
                #pragma unroll
                for (int jt = 0; jt < 4; ++jt)
                    #pragma unroll
                    for (int r = 0; r < 4; ++r) {
                        float p = __expf(acc[jt][r] - mnew);
                        ps += p;
                        pa[jt >> 1][(jt & 1) * 4 + r] = (_Float16)p;
                    }
                ps += __shfl_xor(ps, 16);
                ps += __shfl_xor(ps, 32);

                s[mt] = s[mt] * alpha + ps;
                m[mt] = mnew;

                // alpha (c-layout) -> row-layout before rescaling accO
                float alphaD[4];
                #pragma unroll
                for (int r = 0; r < 4; ++r)
                    alphaD[r] = __shfl(alpha, (lane & 48) | (4 * g + r));
                #pragma unroll
                for (int nt = 0; nt < 4; ++nt)
                    #pragma unroll
                    for (int r = 0; r < 4; ++r) accO[mt][nt][r] *= alphaD[r];

                // PV: B-operand is one b128 (permuted Vt columns)
                #pragma unroll
                for (int st = 0; st < 2; ++st) {
                    #pragma unroll
                    for (int nt = 0; nt < 4; ++nt) {
                        f16x8 vb = *(const f16x8*)&Vt[nt * 16 + c][ch * 64 + st * 32 + 8 * g];
                        accO[mt][nt] = __builtin_amdgcn_mfma_f32_16x16x32_f16(pa[st], vb, accO[mt][nt], 0, 0, 0);
                    }
                }
            }
        }
    }

    // ---- epilogue per m-tile: 1/s (c-layout) -> row-layout, store ----
    #pragma unroll
    for (int mt = 0; mt < 2; ++mt) {
        float rcp = 1.0f / s[mt];
        float rcpD[4];
        #pragma unroll
        for (int r = 0; r < 4; ++r)
            rcpD[r] = __shfl(rcp, (lane & 48) | (4 * g + r));

        float* op = outg + (rowb + ww * 128 + wv * 32 + mt * 16) * 64;
        #pragma unroll
        for (int nt = 0; nt < 4; ++nt)
            #pragma unroll
            for (int r = 0; r < 4; ++r)
                op[(size_t)(4 * g + r) * 64 + nt * 16 + c] = accO[mt][nt][r] * rcpD[r];
    }
}

extern "C" void kernel_launch(void* const* d_in, const int* in_sizes, int n_in,
                              void* d_out, int out_size, void* d_ws, size_t ws_size,
                              hipStream_t stream) {
    (void)in_sizes; (void)n_in; (void)out_size; (void)d_ws; (void)ws_size;
    const float* q = (const float*)d_in[0];
    const float* k = (const float*)d_in[1];
    const float* v = (const float*)d_in[2];
    float* out = (float*)d_out;
    dim3 grid(32, 32);  // x = window, y = batch
    la_kernel<<<grid, BDIM, 0, stream>>>(q, k, v, out);
}

// Round 13
// 33.239 us; speedup vs baseline: 1.1636x; 1.1636x over previous
//
#include <hip/hip_runtime.h>
#include <hip/hip_bf16.h>

#define BDIM 512

typedef __attribute__((ext_vector_type(8))) _Float16 f16x8;
typedef __attribute__((ext_vector_type(4))) _Float16 f16x4;
typedef __attribute__((ext_vector_type(4))) float f32x4;

// native v_exp_f32 computes 2^x; __exp2f doesn't exist in HIP (R12 compile fail)
#define EXP2F(x) __builtin_amdgcn_exp2f(x)

// Local windowed attention with RoPE. b=32, n=4096, d=64, WINDOW=128, 1 backward window.
// ONE BLOCK PER WINDOW-PAIR (RoPE relative-position invariance -> middle K/V half
// shared; block-common origin, t in [0,384)). 3 halves in 2 rolling LDS slots
// (72.7KB, 2 blocks/CU). R12 micro-opts on the R9 structure (best: 34.0us):
//  - causal chunk1 skip for waves 0-3 (fully masked; exact; -12.5% compute)
//  - exp2-domain softmax: log2(e) folded into Q scale, native v_exp_f32 everywhere
//  - defer-rescale: skip alpha/shuffles/mul when __all(mx <= m) (exact)
//  - Q loads issued BEFORE staging (vmcnt queue hides them), RoPE'd after
// Carried: swapped QK^T (stats c-layout, accO row-layout, factors shuffled c->row),
// permuted Vt columns (PV B-operand = one ds_read_b128), online softmax, no big
// register payload across barriers (spill sentinel: WRITE_SIZE == output 32.8MB).
__global__ __launch_bounds__(512, 4)
void la_kernel(const float* __restrict__ qg, const float* __restrict__ kg,
               const float* __restrict__ vg, float* __restrict__ outg)
{
    __shared__ _Float16 Ks[2][128][72];   // 36864 B
    __shared__ _Float16 Vt[2][64][140];   // 35840 B   total 72704 B

    const int wp = blockIdx.x, bb = blockIdx.y;
    const int tid = threadIdx.x;
    const int wv = tid >> 6, lane = tid & 63, g = lane >> 4, c = lane & 15;
    const int base = 256 * wp - 128;      // phys row of t=0 (block-common origin)
    const float NEG = -3.0e38f;
    const float NLT32 = -0.28782313662425572f;   // -ln(10000)/32
    const float QSCALE = 0.125f * 1.4426950408889634f;  // d^-0.5 * log2(e)
    const size_t rowb = (size_t)bb * 4096;

    // hoisted inverse frequencies
    const int cbK = (tid & 7) << 2;
    float invfK[4];
    #pragma unroll
    for (int u = 0; u < 4; ++u) invfK[u] = __expf((float)(cbK + u) * NLT32);
    float invfQ[8];
    #pragma unroll
    for (int u = 0; u < 8; ++u) invfQ[u] = __expf((float)(8 * g + u) * NLT32);

    const int jqV = tid >> 4, eqV = tid & 15;
    const int colbV = ((jqV & 24) << 2) + 8 * (jqV & 3) + 4 * ((jqV >> 2) & 1);

    const int qrow = wv * 16 + c;

    // ---- stage physical half mm (t = 128*mm + jloc) into slot mm&1 ----
    auto stage = [&](int mm) {
        int sl = mm & 1;
        #pragma unroll
        for (int it = 0; it < 2; ++it) {
            int j = (tid + it * 512) >> 3;         // 0..127
            int t = 128 * mm + j;
            const float* p = kg + (rowb + base + t) * 64 + cbK;
            float4 x1 = *(const float4*)p;
            float4 x2 = *(const float4*)(p + 32);
            const float* x1p = &x1.x;
            const float* x2p = &x2.x;
            f16x4 lo, hi;
            #pragma unroll
            for (int u = 0; u < 4; ++u) {
                float sn, cs; __sincosf((float)t * invfK[u], &sn, &cs);
                lo[u] = (_Float16)(x1p[u] * cs - x2p[u] * sn);
                hi[u] = (_Float16)(x2p[u] * cs + x1p[u] * sn);
            }
            *(f16x4*)&Ks[sl][j][cbK]      = lo;
            *(f16x4*)&Ks[sl][j][cbK + 32] = hi;
        }
        float4 x[4];
        #pragma unroll
        for (int w = 0; w < 4; ++w)
            x[w] = *(const float4*)(vg + (rowb + base + 128 * mm + 4 * jqV + w) * 64 + 4 * eqV);
        #pragma unroll
        for (int u = 0; u < 4; ++u) {
            f16x4 o;
            o[0] = (_Float16)((const float*)&x[0])[u];
            o[1] = (_Float16)((const float*)&x[1])[u];
            o[2] = (_Float16)((const float*)&x[2])[u];
            o[3] = (_Float16)((const float*)&x[3])[u];
            *(f16x4*)&Vt[sl][4 * eqV + u][colbV] = o;
        }
    };

    // ---- Q: split load / RoPE ----
    auto loadQraw = [&](int wi, float4* qr) {
        const int tq = 128 * (wi + 1) + qrow;
        const float* p = qg + (rowb + base + tq) * 64 + 8 * g;
        qr[0] = *(const float4*)p;
        qr[1] = *(const float4*)(p + 4);
        qr[2] = *(const float4*)(p + 32);
        qr[3] = *(const float4*)(p + 36);
    };
    auto ropeQ = [&](int wi, const float4* qr, f16x8& qa0, f16x8& qa1) {
        const int tq = 128 * (wi + 1) + qrow;
        float ra[8] = {qr[0].x,qr[0].y,qr[0].z,qr[0].w,qr[1].x,qr[1].y,qr[1].z,qr[1].w};
        float rb[8] = {qr[2].x,qr[2].y,qr[2].z,qr[2].w,qr[3].x,qr[3].y,qr[3].z,qr[3].w};
        #pragma unroll
        for (int u = 0; u < 8; ++u) {
            float sn, cs; __sincosf((float)tq * invfQ[u], &sn, &cs);
            float a = ra[u] * QSCALE, b = rb[u] * QSCALE;
            qa0[u] = (_Float16)(a * cs - b * sn);
            qa1[u] = (_Float16)(b * cs + a * sn);
        }
    };

    // ---- compute one window (wi): keys = halves wi, wi+1; exp2-domain scores ----
    auto computeWin = [&](int wi, f16x8 qa0, f16x8 qa1) {
        f32x4 accO[4];
        #pragma unroll
        for (int nt = 0; nt < 4; ++nt) accO[nt] = (f32x4){0.f,0.f,0.f,0.f};
        float m = NEG, s = 0.f;

        #pragma unroll 1
        for (int mm = wi; mm <= wi + 1; ++mm) {
            if (wp == 0 && mm == 0) continue;      // half P0 of block 0 is padding
            const int sl = mm & 1;
            const bool causal = (mm == wi + 1);

            #pragma unroll
            for (int ch = 0; ch < 2; ++ch) {
                // exact skip: causal chunk1 fully masked for waves 0-3 (qrow <= 63)
                if (causal && ch == 1 && wv < 4) continue;

                f32x4 acc[4];
                #pragma unroll
                for (int jt = 0; jt < 4; ++jt) acc[jt] = (f32x4){0.f,0.f,0.f,0.f};

                #pragma unroll
                for (int jt = 0; jt < 4; ++jt) {
                    int row = ch * 64 + jt * 16 + c;
                    f16x8 kb0 = *(const f16x8*)&Ks[sl][row][8 * g];
                    f16x8 kb1 = *(const f16x8*)&Ks[sl][row][32 + 8 * g];
                    acc[jt] = __builtin_amdgcn_mfma_f32_16x16x32_f16(kb0, qa0, acc[jt], 0, 0, 0);
                    acc[jt] = __builtin_amdgcn_mfma_f32_16x16x32_f16(kb1, qa1, acc[jt], 0, 0, 0);
                }

                if (causal) {
                    #pragma unroll
                    for (int jt = 0; jt < 4; ++jt)
                        #pragma unroll
                        for (int r = 0; r < 4; ++r) {
                            int jj = ch * 64 + jt * 16 + 4 * g + r;
                            if (jj > qrow) acc[jt][r] = NEG;
                        }
                }

                float mx = NEG;
                #pragma unroll
                for (int jt = 0; jt < 4; ++jt)
                    #pragma unroll
                    for (int r = 0; r < 4; ++r) mx = fmaxf(mx, acc[jt][r]);
                mx = fmaxf(mx, __shfl_xor(mx, 16));
                mx = fmaxf(mx, __shfl_xor(mx, 32));

                const bool grow = !__all(mx <= m); // wave-uniform
                float mnew = grow ? fmaxf(m, mx) : m;

                float ps = 0.f;
                f16x8 pa[2];
                #pragma unroll
                for (int jt = 0; jt < 4; ++jt)
                    #pragma unroll
                    for (int r = 0; r < 4; ++r) {
                        float p = EXP2F(acc[jt][r] - mnew);    // masked -> 0
                        ps += p;
                        pa[jt >> 1][(jt & 1) * 4 + r] = (_Float16)p;
                    }
                ps += __shfl_xor(ps, 16);
                ps += __shfl_xor(ps, 32);

                if (grow) {
                    float alpha = EXP2F(m - mnew);     // first real chunk -> 0
                    s = s * alpha + ps;
                    m = mnew;
                    float alphaD[4];
                    #pragma unroll
                    for (int r = 0; r < 4; ++r)
                        alphaD[r] = __shfl(alpha, (lane & 48) | (4 * g + r));
                    #pragma unroll
                    for (int nt = 0; nt < 4; ++nt)
                        #pragma unroll
                        for (int r = 0; r < 4; ++r) accO[nt][r] *= alphaD[r];
                } else {
                    s += ps;
                }

                #pragma unroll
                for (int st = 0; st < 2; ++st) {
                    #pragma unroll
                    for (int nt = 0; nt < 4; ++nt) {
                        f16x8 vb = *(const f16x8*)&Vt[sl][nt * 16 + c][ch * 64 + st * 32 + 8 * g];
                        accO[nt] = __builtin_amdgcn_mfma_f32_16x16x32_f16(pa[st], vb, accO[nt], 0, 0, 0);
                    }
                }
            }
        }

        float rcp = 1.0f / s;
        float rcpD[4];
        #pragma unroll
        for (int r = 0; r < 4; ++r)
            rcpD[r] = __shfl(rcp, (lane & 48) | (4 * g + r));

        float* op = outg + (rowb + base + 128 * (wi + 1) + wv * 16) * 64;
        #pragma unroll
        for (int nt = 0; nt < 4; ++nt)
            #pragma unroll
            for (int r = 0; r < 4; ++r)
                op[(size_t)(4 * g + r) * 64 + nt * 16 + c] = accO[nt][r] * rcpD[r];
    };

    // ---- schedule: Qraw(0) -> stage P0,P1 -> ropeQ(0) -> win0 -> Qraw(1) ->
    //      stage P2 -> ropeQ(1) -> win1 ----
    float4 qr[4];
    loadQraw(0, qr);                      // issued first; hidden under staging waits
    if (wp > 0) stage(0);
    stage(1);
    f16x8 qA, qB;
    ropeQ(0, qr, qA, qB);
    __syncthreads();
    computeWin(0, qA, qB);
    loadQraw(1, qr);                      // issue win1's Q before the barrier
    __syncthreads();                      // all reads of slot0 done
    stage(2);
    ropeQ(1, qr, qA, qB);
    __syncthreads();
    computeWin(1, qA, qB);
}

extern "C" void kernel_launch(void* const* d_in, const int* in_sizes, int n_in,
                              void* d_out, int out_size, void* d_ws, size_t ws_size,
                              hipStream_t stream) {
    (void)in_sizes; (void)n_in; (void)out_size; (void)d_ws; (void)ws_size;
    const float* q = (const float*)d_in[0];
    const float* k = (const float*)d_in[1];
    const float* v = (const float*)d_in[2];
    float* out = (float*)d_out;
    dim3 grid(16, 32);  // x = window-pair, y = batch
    la_kernel<<<grid, BDIM, 0, stream>>>(q, k, v, out);
}